// Round 10
// baseline (255.568 us; speedup 1.0000x reference)
//
#include <hip/hip_runtime.h>

// out[i] = x0*(1-x0) + x1*(1-x1)   (A = 1.0)
// ROUND-10 DIAGNOSTIC: launch the identical kernel 3x (distinct symbols, all
// idempotently writing d_out). Headline dur_us = harness_resets + T1 + T2 + T3.
// Baseline headline was 205 us with one launch; the delta /2 measures the
// kernel's own (L3-warm) duration, which the top-5 profile view hides below
// the ~80 us harness poison-fills. This discriminates T_kernel ~30 us (at
// roofline) from ~70 us (2.4x off).

typedef float f32x4 __attribute__((ext_vector_type(4)));

#define POI2D_BODY(NAME)                                                        \
__global__ void __launch_bounds__(256) NAME(const float* __restrict__ in,       \
                                            float* __restrict__ out,            \
                                            int n_vec4) {                       \
    const int v = blockIdx.x * blockDim.x + threadIdx.x;                        \
    if (v < n_vec4) {                                                           \
        const f32x4* in4 = reinterpret_cast<const f32x4*>(in) + 2 * (size_t)v;  \
        f32x4 a = in4[0];                                                       \
        f32x4 b = in4[1];                                                       \
        f32x4 r;                                                                \
        r.x = fmaf(a.x, 1.0f - a.x, a.y * (1.0f - a.y));                        \
        r.y = fmaf(a.z, 1.0f - a.z, a.w * (1.0f - a.w));                        \
        r.z = fmaf(b.x, 1.0f - b.x, b.y * (1.0f - b.y));                        \
        r.w = fmaf(b.z, 1.0f - b.z, b.w * (1.0f - b.w));                        \
        reinterpret_cast<f32x4*>(out)[v] = r;                                   \
    }                                                                           \
}

POI2D_BODY(poi2d_a)
POI2D_BODY(poi2d_b)
POI2D_BODY(poi2d_c)

__global__ void poi2d_tail_kernel(const float* __restrict__ in,
                                  float* __restrict__ out,
                                  int start, int n) {
    int i = start + blockIdx.x * blockDim.x + threadIdx.x;
    if (i < n) {
        float x0 = in[2 * (size_t)i];
        float x1 = in[2 * (size_t)i + 1];
        out[i] = fmaf(x0, 1.0f - x0, x1 * (1.0f - x1));
    }
}

extern "C" void kernel_launch(void* const* d_in, const int* in_sizes, int n_in,
                              void* d_out, int out_size, void* d_ws, size_t ws_size,
                              hipStream_t stream) {
    const float* in = (const float*)d_in[0];
    float* out = (float*)d_out;
    const int n = out_size;
    const int n_vec4 = n / 4;

    const int block = 256;
    const int grid = (n_vec4 + block - 1) / block;   // 16384 blocks for N=2^24
    if (grid > 0) {
        poi2d_a<<<grid, block, 0, stream>>>(in, out, n_vec4);
        poi2d_b<<<grid, block, 0, stream>>>(in, out, n_vec4);   // idempotent repeat
        poi2d_c<<<grid, block, 0, stream>>>(in, out, n_vec4);   // idempotent repeat
    }

    const int tail_start = n_vec4 * 4;
    const int n_tail = n - tail_start;
    if (n_tail > 0) {
        int tgrid = (n_tail + block - 1) / block;
        poi2d_tail_kernel<<<tgrid, block, 0, stream>>>(in, out, tail_start, n);
    }
}

// Round 11
// 204.392 us; speedup vs baseline: 1.2504x; 1.2504x over previous
//
#include <hip/hip_runtime.h>

// out[i] = -A * (x0^2 - x0 + x1^2 - x1) = x0*(1-x0) + x1*(1-x1)   (A = 1.0)
// Memory-bound elementwise map: 12 B/output (8 read + 4 write).
// Exact-grid launch: one vec4-group (4 outputs) per thread ->
// 2x 16B coalesced loads + 1x 16B coalesced store.
//
// MEASURED (round-10 triple-launch diagnostic): T_kernel ~= 25.3 us L3-warm
// (255.6-204.9 us over 2 extra launches), vs 30 us HBM roofline for the
// 192 MB/iter stream -> at/under the memory roofline (L3-assisted).
// Headline 205 us is dominated by harness re-poison/restore fills (~80 us
// each, visible in profile top-5); kernel code cannot reduce that.

typedef float f32x4 __attribute__((ext_vector_type(4)));

__global__ void __launch_bounds__(256) poi2d_kernel(const float* __restrict__ in,
                                                    float* __restrict__ out,
                                                    int n_vec4) {
    const int v = blockIdx.x * blockDim.x + threadIdx.x;
    if (v < n_vec4) {
        const f32x4* in4 = reinterpret_cast<const f32x4*>(in) + 2 * (size_t)v;
        f32x4 a = in4[0];   // pairs (x0,x1) for outputs 4v, 4v+1
        f32x4 b = in4[1];   // pairs for outputs 4v+2, 4v+3
        f32x4 r;
        r.x = fmaf(a.x, 1.0f - a.x, a.y * (1.0f - a.y));
        r.y = fmaf(a.z, 1.0f - a.z, a.w * (1.0f - a.w));
        r.z = fmaf(b.x, 1.0f - b.x, b.y * (1.0f - b.y));
        r.w = fmaf(b.z, 1.0f - b.z, b.w * (1.0f - b.w));
        reinterpret_cast<f32x4*>(out)[v] = r;
    }
}

// Tail kernel only needed if n % 4 != 0 (not the case for N=16777216, but safe).
__global__ void poi2d_tail_kernel(const float* __restrict__ in,
                                  float* __restrict__ out,
                                  int start, int n) {
    int i = start + blockIdx.x * blockDim.x + threadIdx.x;
    if (i < n) {
        float x0 = in[2 * (size_t)i];
        float x1 = in[2 * (size_t)i + 1];
        out[i] = fmaf(x0, 1.0f - x0, x1 * (1.0f - x1));
    }
}

extern "C" void kernel_launch(void* const* d_in, const int* in_sizes, int n_in,
                              void* d_out, int out_size, void* d_ws, size_t ws_size,
                              hipStream_t stream) {
    const float* in = (const float*)d_in[0];
    float* out = (float*)d_out;
    const int n = out_size;            // number of output rows (= N)
    const int n_vec4 = n / 4;

    const int block = 256;
    const int grid = (n_vec4 + block - 1) / block;   // exact grid: 16384 blocks for N=2^24
    if (grid > 0) {
        poi2d_kernel<<<grid, block, 0, stream>>>(in, out, n_vec4);
    }

    const int tail_start = n_vec4 * 4;
    const int n_tail = n - tail_start;
    if (n_tail > 0) {
        int tgrid = (n_tail + block - 1) / block;
        poi2d_tail_kernel<<<tgrid, block, 0, stream>>>(in, out, tail_start, n);
    }
}